// Round 6
// baseline (129.227 us; speedup 1.0000x reference)
//
#include <hip/hip_runtime.h>
#include <cstdint>

typedef uint16_t u16;
typedef __attribute__((ext_vector_type(8))) short short8;
typedef __attribute__((ext_vector_type(4))) float f32x4;

__device__ __forceinline__ u16 f2bf(float f) {
  uint32_t u = __float_as_uint(f);
  u += 0x7fff + ((u >> 16) & 1);   // RNE
  return (u16)(u >> 16);
}
__device__ __forceinline__ float b2f(u16 h) {
  return __uint_as_float(((uint32_t)h) << 16);
}

#define GLL16(gp, lp) __builtin_amdgcn_global_load_lds( \
    (__attribute__((address_space(1))) void*)(gp), \
    (__attribute__((address_space(3))) void*)(lp), 16, 0, 0)

#define SBAR()       __builtin_amdgcn_s_barrier()
#define WAIT_LGKM0() asm volatile("s_waitcnt lgkmcnt(0)" ::: "memory")
#define WAIT_VM(N)   asm volatile("s_waitcnt vmcnt(" #N ")" ::: "memory")
#define MEMBAR()     asm volatile("" ::: "memory")

// ---------------- fused f32 -> bf16 convert ----------------
__global__ void cvt_all(const float* __restrict__ x,  const float* __restrict__ wq,
                        const float* __restrict__ wk, const float* __restrict__ wv,
                        const float* __restrict__ wo,
                        u16* __restrict__ xb, u16* __restrict__ wcat, u16* __restrict__ wob) {
  int i = blockIdx.x * 256 + threadIdx.x;
  const float4* src; ushort4* dst; int off;
  if (i < 1048576)      { src = (const float4*)x;  dst = (ushort4*)xb;              off = i; }
  else if (i < 1310720) { src = (const float4*)wq; dst = (ushort4*)wcat;            off = i - 1048576; }
  else if (i < 1572864) { src = (const float4*)wk; dst = (ushort4*)wcat + 262144;   off = i - 1310720; }
  else if (i < 1835008) { src = (const float4*)wv; dst = (ushort4*)wcat + 524288;   off = i - 1572864; }
  else                  { src = (const float4*)wo; dst = (ushort4*)wob;             off = i - 1835008; }
  float4 v = src[off];
  ushort4 o;
  o.x = f2bf(v.x); o.y = f2bf(v.y); o.z = f2bf(v.z); o.w = f2bf(v.w);
  dst[off] = o;
}

// ---------------- 256x256 8-phase GEMM (QKV): C[m][n] = sum_k A[m][k]*B[n][k], K=1024 ----------------
// 512 thr = 8 waves (2M x 4N); wave output 128x64 = acc[8][4] f32x4. BK=64, 16 K-tiles.
// LDS 128 KiB: sm[2 dbuf][A,B][256 rows][64 k], rows 128B, XOR-swizzled byte^=(row&7)<<4
// via pre-swizzled global source (GLL dest linear). Counted vmcnt(6): 3 x 128x64-pieces in
// flight across barriers; raw s_barrier (no drain); lgkmcnt(0) before closing barrier of
// read-phases so staging never overwrites rows still being ds_read.
__global__ __launch_bounds__(512, 2) void gemm_qkv(const u16* __restrict__ Ap,
                                                   const u16* __restrict__ Bp,
                                                   u16* __restrict__ Cp) {
  __shared__ u16 sm[2][2][256 * 64];
  const int tid  = threadIdx.x;
  const int lane = tid & 63, w = tid >> 6;
  const int wr = w >> 2, wc = w & 3;
  const int g = lane >> 4, lr = lane & 15;

  // XCD-aware bijective swizzle (192 % 8 == 0): 24 consecutive tiles per XCD
  const int id = blockIdx.x;
  const int sw = (id & 7) * 24 + (id >> 3);
  const int row0 = (sw % 16) * 256;   // M tiles: 4096/256 = 16
  const int col0 = (sw / 16) * 256;   // N tiles: 3072/256 = 12

  f32x4 acc[8][4];
  #pragma unroll
  for (int m = 0; m < 8; ++m)
    #pragma unroll
    for (int n = 0; n < 4; ++n) acc[m][n] = (f32x4){0.f, 0.f, 0.f, 0.f};

  // stage one 128x64 piece (16 KiB) of K-tile kt: piece 0=A-half0,1=A-half1,2=B-half0,3=B-half1
  auto STAGE = [&](int kt, int bufi, int piece) {
    if (kt >= 16) return;
    const int ab = piece >> 1, half = piece & 1;
    const u16* __restrict__ src = ab ? Bp : Ap;
    const int rb = (ab ? col0 : row0) + half * 128;
    u16* lds = &sm[bufi][ab][half * 128 * 64];
    #pragma unroll
    for (int j = 0; j < 2; ++j) {
      int r  = j * 64 + w * 8 + (lane >> 3);                 // row in piece 0..127
      int sb = ((lane & 7) << 4) ^ ((r & 7) << 4);           // pre-swizzled source byte col
      const u16* gp = src + (size_t)(rb + r) * 1024 + kt * 64 + (sb >> 1);
      GLL16(gp, lds + (j * 512 + w * 64) * 8);               // wave-uniform base, lane*16B
    }
  };

  short8 a[8][2], b[4][2];

#define RDA(BUF) do { \
    _Pragma("unroll") for (int mm = 0; mm < 8; ++mm) \
      _Pragma("unroll") for (int kh = 0; kh < 2; ++kh) { \
        int row = wr * 128 + mm * 16 + lr; \
        int col = (kh * 64 + g * 16) ^ ((row & 7) << 4); \
        a[mm][kh] = *(const short8*)((const char*)&sm[BUF][0][0] + row * 128 + col); } \
  } while (0)
#define RDB(BUF, N0) do { \
    _Pragma("unroll") for (int nn = N0; nn < N0 + 2; ++nn) \
      _Pragma("unroll") for (int kh = 0; kh < 2; ++kh) { \
        int row = wc * 64 + nn * 16 + lr; \
        int col = (kh * 64 + g * 16) ^ ((row & 7) << 4); \
        b[nn][kh] = *(const short8*)((const char*)&sm[BUF][1][0] + row * 128 + col); } \
  } while (0)
#define QUAD(M0, N0) do { \
    __builtin_amdgcn_s_setprio(1); \
    _Pragma("unroll") for (int mm = 0; mm < 4; ++mm) \
      _Pragma("unroll") for (int nn = 0; nn < 2; ++nn) \
        _Pragma("unroll") for (int kh = 0; kh < 2; ++kh) \
          acc[M0 + mm][N0 + nn] = __builtin_amdgcn_mfma_f32_16x16x32_bf16( \
              a[M0 + mm][kh], b[N0 + nn][kh], acc[M0 + mm][N0 + nn], 0, 0, 0); \
    __builtin_amdgcn_s_setprio(0); \
  } while (0)

  // prologue: tile0 all 4 pieces + tile1 pieces A0,A1,B0 (B1 issued at P1)
  STAGE(0, 0, 0); STAGE(0, 0, 1); STAGE(0, 0, 2); STAGE(0, 0, 3);
  STAGE(1, 1, 0); STAGE(1, 1, 1); STAGE(1, 1, 2);
  WAIT_VM(6); SBAR(); MEMBAR();

  for (int i = 0; i < 8; ++i) {
    const int T = 2 * i;
    // ---- P1 (tile T, buf0): read all A + B n0-1; stage (T+1).B1 ----
    RDA(0); RDB(0, 0);
    STAGE(T + 1, 1, 3);
    MEMBAR(); SBAR(); MEMBAR();
    QUAD(0, 0);
    WAIT_LGKM0(); SBAR(); MEMBAR();
    // ---- P2: read B n2-3; stage (T+2).A0 ----
    RDB(0, 2);
    STAGE(T + 2, 0, 0);
    MEMBAR(); SBAR(); MEMBAR();
    QUAD(4, 0);
    WAIT_LGKM0(); SBAR(); MEMBAR();
    // ---- P3: stage (T+2).A1 ----
    STAGE(T + 2, 0, 1);
    MEMBAR(); SBAR(); MEMBAR();
    QUAD(0, 2);
    MEMBAR(); SBAR(); MEMBAR();
    // ---- P4: stage (T+2).B0; checkpoint ----
    STAGE(T + 2, 0, 2);
    MEMBAR(); SBAR(); MEMBAR();
    QUAD(4, 2);
    if (i == 7) { WAIT_VM(0); } else { WAIT_VM(6); }
    SBAR(); MEMBAR();

    // ---- P5 (tile T+1, buf1): read all A + B n0-1; stage (T+2).B1 ----
    RDA(1); RDB(1, 0);
    STAGE(T + 2, 0, 3);
    MEMBAR(); SBAR(); MEMBAR();
    QUAD(0, 0);
    WAIT_LGKM0(); SBAR(); MEMBAR();
    // ---- P6: read B n2-3; stage (T+3).A0 ----
    RDB(1, 2);
    STAGE(T + 3, 1, 0);
    MEMBAR(); SBAR(); MEMBAR();
    QUAD(4, 0);
    WAIT_LGKM0(); SBAR(); MEMBAR();
    // ---- P7: stage (T+3).A1 ----
    STAGE(T + 3, 1, 1);
    MEMBAR(); SBAR(); MEMBAR();
    QUAD(0, 2);
    MEMBAR(); SBAR(); MEMBAR();
    // ---- P8: stage (T+3).B0; checkpoint ----
    STAGE(T + 3, 1, 2);
    MEMBAR(); SBAR(); MEMBAR();
    QUAD(4, 2);
    if (i < 7) { WAIT_VM(6); }
    SBAR(); MEMBAR();
  }
#undef RDA
#undef RDB
#undef QUAD

  // epilogue: C row = row0 + wr*128 + m*16 + g*4 + ri, col = col0 + wc*64 + n*16 + lr
  #pragma unroll
  for (int m = 0; m < 8; ++m)
    #pragma unroll
    for (int n = 0; n < 4; ++n)
      #pragma unroll
      for (int ri = 0; ri < 4; ++ri) {
        int rr = row0 + wr * 128 + m * 16 + g * 4 + ri;
        int cc = col0 + wc * 64 + n * 16 + lr;
        Cp[(size_t)rr * 3072 + cc] = f2bf(acc[m][n][ri]);
      }
}

// ---------------- 128x128 GEMM (proj): C[m][n] = sum_k A[m][k]*B[n][k], f32 out ----------------
__global__ __launch_bounds__(256) void gemm_bt(const u16* __restrict__ A, const u16* __restrict__ B,
                                               float* __restrict__ Cout, int M, int N, int K) {
  __shared__ u16 lA[128 * 32];
  __shared__ u16 lB[128 * 32];
  const int tid  = threadIdx.x;
  const int lane = tid & 63, w = tid >> 6;
  const int wr = w >> 1, wc = w & 1;
  const int g = lane >> 4, lr = lane & 15;
  const int row0 = blockIdx.x * 128, col0 = blockIdx.y * 128;

  f32x4 acc[4][4];
  #pragma unroll
  for (int i = 0; i < 4; ++i)
    #pragma unroll
    for (int j = 0; j < 4; ++j) acc[i][j] = (f32x4){0.f, 0.f, 0.f, 0.f};

  for (int kt = 0; kt < K; kt += 32) {
    __syncthreads();
    #pragma unroll
    for (int it = 0; it < 2; ++it) {
      int c  = it * 256 + tid;
      int r  = c >> 2;
      int k8 = (c & 3) << 3;
      const u16* ga = A + (size_t)(row0 + r) * K + kt + k8;
      const u16* gb = B + (size_t)(col0 + r) * K + kt + k8;
      u16* la = lA + (size_t)(it * 256 + w * 64) * 8;
      u16* lb = lB + (size_t)(it * 256 + w * 64) * 8;
      GLL16(ga, la);
      GLL16(gb, lb);
    }
    __syncthreads();

    short8 af[4], bf[4];
    #pragma unroll
    for (int i = 0; i < 4; ++i) {
      af[i] = *(const short8*)(lA + (wr * 64 + i * 16 + lr) * 32 + g * 8);
      bf[i] = *(const short8*)(lB + (wc * 64 + i * 16 + lr) * 32 + g * 8);
    }
    #pragma unroll
    for (int i = 0; i < 4; ++i)
      #pragma unroll
      for (int j = 0; j < 4; ++j)
        acc[i][j] = __builtin_amdgcn_mfma_f32_16x16x32_bf16(af[i], bf[j], acc[i][j], 0, 0, 0);
  }

  #pragma unroll
  for (int i = 0; i < 4; ++i)
    #pragma unroll
    for (int j = 0; j < 4; ++j)
      #pragma unroll
      for (int ri = 0; ri < 4; ++ri) {
        int rr = row0 + wr * 64 + i * 16 + g * 4 + ri;
        int cc = col0 + wc * 64 + j * 16 + lr;
        Cout[(size_t)rr * N + cc] = acc[i][j][ri];
      }
}

// ---------------- Flash sliding-window attention (v3, unchanged) ----------------
__global__ __launch_bounds__(256) void attn_swa(const u16* __restrict__ QKV, u16* __restrict__ O) {
  const int S = 2048;
  const int qb = blockIdx.x * 64;
  const int b = blockIdx.y >> 4, h = blockIdx.y & 15;
  const int tid = threadIdx.x;
  const int lane = tid & 63, w = tid >> 6;
  const int g = lane >> 4, lr = lane & 15;

  __shared__ u16 Klds[2][64 * 64];   // [64 keys][64 d], rows 128B, byte ^= (row&7)<<4
  __shared__ u16 Vt[64][72];         // V^T [d][key], pitch 144B (single buffer)
  __shared__ u16 Plds[4][16][72];    // per-wave P^T [q][key 0..63], pitch 144B

  const u16* Qb = QKV + (size_t)b * S * 3072 + h * 64;
  const u16* Kb = QKV + (size_t)b * S * 3072 + 1024 + h * 64;
  const u16* Vb = QKV + (size_t)b * S * 3072 + 2048 + h * 64;

  const int qw = qb + w * 16;
  short8 qf0 = *(const short8*)(Qb + (size_t)(qw + lr) * 3072 + g * 8);
  short8 qf1 = *(const short8*)(Qb + (size_t)(qw + lr) * 3072 + 32 + g * 8);

  float ls = 0.f;
  f32x4 accO[4];
  #pragma unroll
  for (int i = 0; i < 4; ++i) accO[i] = (f32x4){0.f, 0.f, 0.f, 0.f};

  int ks = qb - 511; if (ks < 0) ks = 0; ks &= ~63;
  const int ke = qb + 63;
  const int nt = ((ke - ks) >> 6) + 1;

  short8 vreg0, vreg1;

  auto STAGE_K = [&](int kb, int buf) {
    #pragma unroll
    for (int c = 0; c < 2; ++c) {
      int r  = c * 32 + w * 8 + (lane >> 3);
      int sb = ((lane & 7) << 4) ^ ((r & 7) << 4);
      const u16* gp = Kb + (size_t)(kb + r) * 3072 + (sb >> 1);
      u16* lp = Klds[buf] + c * 2048 + w * 512;
      GLL16(gp, lp);
    }
  };
  auto LOAD_V = [&](int kb) {
    vreg0 = *(const short8*)(Vb + (size_t)(kb + lane) * 3072 + w * 8);
    vreg1 = *(const short8*)(Vb + (size_t)(kb + lane) * 3072 + w * 8 + 32);
  };
  auto WRITE_V = [&]() {
    #pragma unroll
    for (int j = 0; j < 8; ++j) Vt[w * 8 + j][lane]      = (u16)vreg0[j];
    #pragma unroll
    for (int j = 0; j < 8; ++j) Vt[w * 8 + 32 + j][lane] = (u16)vreg1[j];
  };

  STAGE_K(ks, 0);
  LOAD_V(ks);
  __syncthreads();
  WRITE_V();
  __syncthreads();

  int cur = 0, kb = ks;
  for (int t = 0; t < nt; ++t, kb += 64) {
    const int nxt = cur ^ 1;
    const bool more = (t + 1 < nt);
    if (more) { STAGE_K(kb + 64, nxt); LOAD_V(kb + 64); }

    float p[4][4];
    #pragma unroll
    for (int st = 0; st < 4; ++st) {
      f32x4 c4 = (f32x4){0.f, 0.f, 0.f, 0.f};
      int r = st * 16 + lr;
      int swz = (r & 7) << 4;
      const char* krow = (const char*)(Klds[cur]) + r * 128;
      short8 kf0 = *(const short8*)(krow + ((g * 16) ^ swz));
      short8 kf1 = *(const short8*)(krow + ((64 + g * 16) ^ swz));
      __builtin_amdgcn_s_setprio(1);
      c4 = __builtin_amdgcn_mfma_f32_16x16x32_bf16(kf0, qf0, c4, 0, 0, 0);
      c4 = __builtin_amdgcn_mfma_f32_16x16x32_bf16(kf1, qf1, c4, 0, 0, 0);
      __builtin_amdgcn_s_setprio(0);
      const int qi = qw + lr;
      #pragma unroll
      for (int ri = 0; ri < 4; ++ri) {
        int ki = kb + st * 16 + g * 4 + ri;
        bool ok = (ki <= qi) && (qi - ki < 512);
        float e = __builtin_amdgcn_exp2f(c4[ri] * 0.18033688011112042f);
        p[st][ri] = ok ? e : 0.f;
      }
    }

    {
      float s = 0.f;
      #pragma unroll
      for (int st = 0; st < 4; ++st)
        #pragma unroll
        for (int ri = 0; ri < 4; ++ri) s += p[st][ri];
      s += __shfl_xor(s, 16);
      s += __shfl_xor(s, 32);
      ls += s;
    }

    #pragma unroll
    for (int st = 0; st < 4; ++st) {
      uint32_t lo = (uint32_t)f2bf(p[st][0]) | ((uint32_t)f2bf(p[st][1]) << 16);
      uint32_t hi = (uint32_t)f2bf(p[st][2]) | ((uint32_t)f2bf(p[st][3]) << 16);
      uint2 u2; u2.x = lo; u2.y = hi;
      *(uint2*)(&Plds[w][lr][st * 16 + g * 4]) = u2;
    }

    short8 pf0 = *(const short8*)(&Plds[w][lr][g * 8]);
    short8 pf1 = *(const short8*)(&Plds[w][lr][32 + g * 8]);
    __builtin_amdgcn_s_setprio(1);
    #pragma unroll
    for (int dt = 0; dt < 4; ++dt) {
      short8 vf0 = *(const short8*)(&Vt[dt * 16 + lr][g * 8]);
      short8 vf1 = *(const short8*)(&Vt[dt * 16 + lr][32 + g * 8]);
      accO[dt] = __builtin_amdgcn_mfma_f32_16x16x32_bf16(pf0, vf0, accO[dt], 0, 0, 0);
      accO[dt] = __builtin_amdgcn_mfma_f32_16x16x32_bf16(pf1, vf1, accO[dt], 0, 0, 0);
    }
    __builtin_amdgcn_s_setprio(0);

    __syncthreads();
    if (more) WRITE_V();
    __syncthreads();
    cur = nxt;
  }

  float lsq[4];
  #pragma unroll
  for (int ri = 0; ri < 4; ++ri) lsq[ri] = __shfl(ls, g * 4 + ri);
  #pragma unroll
  for (int dt = 0; dt < 4; ++dt)
    #pragma unroll
    for (int ri = 0; ri < 4; ++ri) {
      int qi = qw + g * 4 + ri;
      O[(size_t)(b * S + qi) * 1024 + h * 64 + dt * 16 + lr] = f2bf(accO[dt][ri] / lsq[ri]);
    }
}

// ---------------- launch ----------------
extern "C" void kernel_launch(void* const* d_in, const int* in_sizes, int n_in,
                              void* d_out, int out_size, void* d_ws, size_t ws_size,
                              hipStream_t stream) {
  const float* x  = (const float*)d_in[0];
  const float* Wq = (const float*)d_in[1];
  const float* Wk = (const float*)d_in[2];
  const float* Wv = (const float*)d_in[3];
  const float* Wo = (const float*)d_in[4];

  char* ws = (char*)d_ws;
  u16* xb   = (u16*)(ws);                    //  8 MiB: x bf16 [4096][1024]
  u16* Wcat = (u16*)(ws + (8  << 20));       //  6 MiB: [Wq;Wk;Wv] bf16 [3072][1024]
  u16* Wob  = (u16*)(ws + (14 << 20));       //  2 MiB: Wo bf16 [1024][1024]
  u16* QKV  = (u16*)(ws + (16 << 20));       // 24 MiB: [4096][3072]
  u16* Oatt = (u16*)(ws + (40 << 20));       //  8 MiB: [4096][1024]

  cvt_all<<<8192, 256, 0, stream>>>(x, Wq, Wk, Wv, Wo, xb, Wcat, Wob);
  gemm_qkv<<<192, 512, 0, stream>>>(xb, Wcat, QKV);
  attn_swa<<<dim3(32, 32), 256, 0, stream>>>(QKV, Oatt);
  gemm_bt<<<dim3(32, 8), 256, 0, stream>>>(Oatt, Wob, (float*)d_out, 4096, 1024, 1024);
}

// Round 7
// 96.771 us; speedup vs baseline: 1.3354x; 1.3354x over previous
//
#include <hip/hip_runtime.h>
#include <cstdint>

typedef uint16_t u16;
typedef __attribute__((ext_vector_type(8))) short short8;
typedef __attribute__((ext_vector_type(4))) float f32x4;

__device__ __forceinline__ u16 f2bf(float f) {
  uint32_t u = __float_as_uint(f);
  u += 0x7fff + ((u >> 16) & 1);   // RNE
  return (u16)(u >> 16);
}
__device__ __forceinline__ float b2f(u16 h) {
  return __uint_as_float(((uint32_t)h) << 16);
}

#define GLL16(gp, lp) __builtin_amdgcn_global_load_lds( \
    (__attribute__((address_space(1))) void*)(gp), \
    (__attribute__((address_space(3))) void*)(lp), 16, 0, 0)

#define SBAR()       __builtin_amdgcn_s_barrier()
#define WAIT_LGKM0() asm volatile("s_waitcnt lgkmcnt(0)" ::: "memory")
#define WAIT_VM(N)   asm volatile("s_waitcnt vmcnt(" #N ")" ::: "memory")
#define MEMBAR()     asm volatile("" ::: "memory")

// ---------------- fused f32 -> bf16 convert ----------------
__global__ void cvt_all(const float* __restrict__ x,  const float* __restrict__ wq,
                        const float* __restrict__ wk, const float* __restrict__ wv,
                        const float* __restrict__ wo,
                        u16* __restrict__ xb, u16* __restrict__ wcat, u16* __restrict__ wob) {
  int i = blockIdx.x * 256 + threadIdx.x;
  const float4* src; ushort4* dst; int off;
  if (i < 1048576)      { src = (const float4*)x;  dst = (ushort4*)xb;              off = i; }
  else if (i < 1310720) { src = (const float4*)wq; dst = (ushort4*)wcat;            off = i - 1048576; }
  else if (i < 1572864) { src = (const float4*)wk; dst = (ushort4*)wcat + 262144;   off = i - 1310720; }
  else if (i < 1835008) { src = (const float4*)wv; dst = (ushort4*)wcat + 524288;   off = i - 1572864; }
  else                  { src = (const float4*)wo; dst = (ushort4*)wob;             off = i - 1835008; }
  float4 v = src[off];
  ushort4 o;
  o.x = f2bf(v.x); o.y = f2bf(v.y); o.z = f2bf(v.z); o.w = f2bf(v.w);
  dst[off] = o;
}

// ---------------- 128x128 counted-vmcnt GEMM: C[m][n] = sum_k A[m][k]*B[n][k] ----------------
// 256 thr = 4 waves (2x2), wave tile 64x64 = acc[4][4]. BK=64, K/64 tiles, double-buffered
// 64 KiB LDS -> 2 blocks/CU resident (TLP). Rows 128B, XOR swizzle byte^=(row&7)<<4 via
// pre-swizzled GLL source + swizzled reads (conflict-free). Steady state: stage tile t+2
// during tile t, counted WAIT_VM(8) (= next tile's 8 GLLs) at tile end -- no vmcnt(0) drain.
// Barrier #1 (after lgkm0) makes all reads of buf[cur] globally done before restaging it.
template<int OUT_BF16>
__global__ __launch_bounds__(256, 2) void gemm128(const u16* __restrict__ A,
                                                  const u16* __restrict__ B,
                                                  void* __restrict__ Cout,
                                                  int N, int K, int ntN) {
  __shared__ u16 sm[2][2][128 * 64];   // [dbuf][A,B][row][k] 64 KiB
  const int tid  = threadIdx.x;
  const int lane = tid & 63, w = tid >> 6;
  const int wr = w >> 1, wc = w & 1;
  const int g = lane >> 4, lr = lane & 15;

  // XCD-aware swizzle (gridDim.x % 8 == 0)
  const int cpx = gridDim.x >> 3;
  const int id  = blockIdx.x;
  const int sw  = (id & 7) * cpx + (id >> 3);
  const int row0 = (sw / ntN) * 128, col0 = (sw % ntN) * 128;
  const int T = K >> 6;

  f32x4 acc[4][4];
  #pragma unroll
  for (int i = 0; i < 4; ++i)
    #pragma unroll
    for (int j = 0; j < 4; ++j) acc[i][j] = (f32x4){0.f, 0.f, 0.f, 0.f};

  // stage K-tile kt into buf: 8 GLL16 per wave (4 rounds x {A,B}); each GLL = 8 rows
  auto STAGE = [&](int kt, int bufi) {
    #pragma unroll
    for (int ab = 0; ab < 2; ++ab) {
      const u16* __restrict__ src = ab ? B : A;
      const int rb = ab ? col0 : row0;
      #pragma unroll
      for (int j = 0; j < 4; ++j) {
        int r  = j * 32 + w * 8 + (lane >> 3);
        int sb = ((lane & 7) << 4) ^ ((r & 7) << 4);   // pre-swizzled source byte col
        const u16* gp = src + (size_t)(rb + r) * K + kt * 64 + (sb >> 1);
        GLL16(gp, &sm[bufi][ab][(size_t)(j * 32 + w * 8) * 64]);
      }
    }
  };

  // prologue
  STAGE(0, 0); STAGE(1, 1);
  WAIT_VM(8); SBAR(); MEMBAR();

  for (int t = 0; t < T; ++t) {
    const int cur = t & 1;
    short8 a[4][2], b[4][2];
    #pragma unroll
    for (int mm = 0; mm < 4; ++mm)
      #pragma unroll
      for (int kh = 0; kh < 2; ++kh) {
        int row = wr * 64 + mm * 16 + lr;
        int col = (kh * 64 + g * 16) ^ ((row & 7) << 4);
        a[mm][kh] = *(const short8*)((const char*)&sm[cur][0][0] + row * 128 + col);
      }
    #pragma unroll
    for (int nn = 0; nn < 4; ++nn)
      #pragma unroll
      for (int kh = 0; kh < 2; ++kh) {
        int row = wc * 64 + nn * 16 + lr;
        int col = (kh * 64 + g * 16) ^ ((row & 7) << 4);
        b[nn][kh] = *(const short8*)((const char*)&sm[cur][1][0] + row * 128 + col);
      }
    WAIT_LGKM0(); MEMBAR(); SBAR(); MEMBAR();   // all waves' reads of buf[cur] done

    if (t + 2 < T) STAGE(t + 2, cur);

    __builtin_amdgcn_s_setprio(1);
    #pragma unroll
    for (int kh = 0; kh < 2; ++kh)
      #pragma unroll
      for (int mm = 0; mm < 4; ++mm)
        #pragma unroll
        for (int nn = 0; nn < 4; ++nn)
          acc[mm][nn] = __builtin_amdgcn_mfma_f32_16x16x32_bf16(
              a[mm][kh], b[nn][kh], acc[mm][nn], 0, 0, 0);
    __builtin_amdgcn_s_setprio(0);

    if (t + 1 < T) {
      if (t + 2 < T) { WAIT_VM(8); } else { WAIT_VM(0); }   // tile t+1 fully landed
      SBAR(); MEMBAR();
    }
  }

  // epilogue: C/D layout col = lane&15, row = (lane>>4)*4 + reg
  #pragma unroll
  for (int i = 0; i < 4; ++i)
    #pragma unroll
    for (int j = 0; j < 4; ++j)
      #pragma unroll
      for (int ri = 0; ri < 4; ++ri) {
        int rr = row0 + wr * 64 + i * 16 + g * 4 + ri;
        int cc = col0 + wc * 64 + j * 16 + lr;
        if (OUT_BF16) ((u16*)Cout)[(size_t)rr * N + cc] = f2bf(acc[i][j][ri]);
        else          ((float*)Cout)[(size_t)rr * N + cc] = acc[i][j][ri];
      }
}

// ---------------- Flash sliding-window attention (v3, unchanged) ----------------
__global__ __launch_bounds__(256) void attn_swa(const u16* __restrict__ QKV, u16* __restrict__ O) {
  const int S = 2048;
  const int qb = blockIdx.x * 64;
  const int b = blockIdx.y >> 4, h = blockIdx.y & 15;
  const int tid = threadIdx.x;
  const int lane = tid & 63, w = tid >> 6;
  const int g = lane >> 4, lr = lane & 15;

  __shared__ u16 Klds[2][64 * 64];   // [64 keys][64 d], rows 128B, byte ^= (row&7)<<4
  __shared__ u16 Vt[64][72];         // V^T [d][key], pitch 144B (single buffer)
  __shared__ u16 Plds[4][16][72];    // per-wave P^T [q][key 0..63], pitch 144B

  const u16* Qb = QKV + (size_t)b * S * 3072 + h * 64;
  const u16* Kb = QKV + (size_t)b * S * 3072 + 1024 + h * 64;
  const u16* Vb = QKV + (size_t)b * S * 3072 + 2048 + h * 64;

  const int qw = qb + w * 16;
  short8 qf0 = *(const short8*)(Qb + (size_t)(qw + lr) * 3072 + g * 8);
  short8 qf1 = *(const short8*)(Qb + (size_t)(qw + lr) * 3072 + 32 + g * 8);

  float ls = 0.f;
  f32x4 accO[4];
  #pragma unroll
  for (int i = 0; i < 4; ++i) accO[i] = (f32x4){0.f, 0.f, 0.f, 0.f};

  int ks = qb - 511; if (ks < 0) ks = 0; ks &= ~63;
  const int ke = qb + 63;
  const int nt = ((ke - ks) >> 6) + 1;

  short8 vreg0, vreg1;

  auto STAGE_K = [&](int kb, int buf) {
    #pragma unroll
    for (int c = 0; c < 2; ++c) {
      int r  = c * 32 + w * 8 + (lane >> 3);
      int sb = ((lane & 7) << 4) ^ ((r & 7) << 4);
      const u16* gp = Kb + (size_t)(kb + r) * 3072 + (sb >> 1);
      u16* lp = Klds[buf] + c * 2048 + w * 512;
      GLL16(gp, lp);
    }
  };
  auto LOAD_V = [&](int kb) {
    vreg0 = *(const short8*)(Vb + (size_t)(kb + lane) * 3072 + w * 8);
    vreg1 = *(const short8*)(Vb + (size_t)(kb + lane) * 3072 + w * 8 + 32);
  };
  auto WRITE_V = [&]() {
    #pragma unroll
    for (int j = 0; j < 8; ++j) Vt[w * 8 + j][lane]      = (u16)vreg0[j];
    #pragma unroll
    for (int j = 0; j < 8; ++j) Vt[w * 8 + 32 + j][lane] = (u16)vreg1[j];
  };

  STAGE_K(ks, 0);
  LOAD_V(ks);
  __syncthreads();
  WRITE_V();
  __syncthreads();

  int cur = 0, kb = ks;
  for (int t = 0; t < nt; ++t, kb += 64) {
    const int nxt = cur ^ 1;
    const bool more = (t + 1 < nt);
    if (more) { STAGE_K(kb + 64, nxt); LOAD_V(kb + 64); }

    float p[4][4];
    #pragma unroll
    for (int st = 0; st < 4; ++st) {
      f32x4 c4 = (f32x4){0.f, 0.f, 0.f, 0.f};
      int r = st * 16 + lr;
      int swz = (r & 7) << 4;
      const char* krow = (const char*)(Klds[cur]) + r * 128;
      short8 kf0 = *(const short8*)(krow + ((g * 16) ^ swz));
      short8 kf1 = *(const short8*)(krow + ((64 + g * 16) ^ swz));
      __builtin_amdgcn_s_setprio(1);
      c4 = __builtin_amdgcn_mfma_f32_16x16x32_bf16(kf0, qf0, c4, 0, 0, 0);
      c4 = __builtin_amdgcn_mfma_f32_16x16x32_bf16(kf1, qf1, c4, 0, 0, 0);
      __builtin_amdgcn_s_setprio(0);
      const int qi = qw + lr;
      #pragma unroll
      for (int ri = 0; ri < 4; ++ri) {
        int ki = kb + st * 16 + g * 4 + ri;
        bool ok = (ki <= qi) && (qi - ki < 512);
        float e = __builtin_amdgcn_exp2f(c4[ri] * 0.18033688011112042f);
        p[st][ri] = ok ? e : 0.f;
      }
    }

    {
      float s = 0.f;
      #pragma unroll
      for (int st = 0; st < 4; ++st)
        #pragma unroll
        for (int ri = 0; ri < 4; ++ri) s += p[st][ri];
      s += __shfl_xor(s, 16);
      s += __shfl_xor(s, 32);
      ls += s;
    }

    #pragma unroll
    for (int st = 0; st < 4; ++st) {
      uint32_t lo = (uint32_t)f2bf(p[st][0]) | ((uint32_t)f2bf(p[st][1]) << 16);
      uint32_t hi = (uint32_t)f2bf(p[st][2]) | ((uint32_t)f2bf(p[st][3]) << 16);
      uint2 u2; u2.x = lo; u2.y = hi;
      *(uint2*)(&Plds[w][lr][st * 16 + g * 4]) = u2;
    }

    short8 pf0 = *(const short8*)(&Plds[w][lr][g * 8]);
    short8 pf1 = *(const short8*)(&Plds[w][lr][32 + g * 8]);
    __builtin_amdgcn_s_setprio(1);
    #pragma unroll
    for (int dt = 0; dt < 4; ++dt) {
      short8 vf0 = *(const short8*)(&Vt[dt * 16 + lr][g * 8]);
      short8 vf1 = *(const short8*)(&Vt[dt * 16 + lr][32 + g * 8]);
      accO[dt] = __builtin_amdgcn_mfma_f32_16x16x32_bf16(pf0, vf0, accO[dt], 0, 0, 0);
      accO[dt] = __builtin_amdgcn_mfma_f32_16x16x32_bf16(pf1, vf1, accO[dt], 0, 0, 0);
    }
    __builtin_amdgcn_s_setprio(0);

    __syncthreads();
    if (more) WRITE_V();
    __syncthreads();
    cur = nxt;
  }

  float lsq[4];
  #pragma unroll
  for (int ri = 0; ri < 4; ++ri) lsq[ri] = __shfl(ls, g * 4 + ri);
  #pragma unroll
  for (int dt = 0; dt < 4; ++dt)
    #pragma unroll
    for (int ri = 0; ri < 4; ++ri) {
      int qi = qw + g * 4 + ri;
      O[(size_t)(b * S + qi) * 1024 + h * 64 + dt * 16 + lr] = f2bf(accO[dt][ri] / lsq[ri]);
    }
}

// ---------------- launch ----------------
extern "C" void kernel_launch(void* const* d_in, const int* in_sizes, int n_in,
                              void* d_out, int out_size, void* d_ws, size_t ws_size,
                              hipStream_t stream) {
  const float* x  = (const float*)d_in[0];
  const float* Wq = (const float*)d_in[1];
  const float* Wk = (const float*)d_in[2];
  const float* Wv = (const float*)d_in[3];
  const float* Wo = (const float*)d_in[4];

  char* ws = (char*)d_ws;
  u16* xb   = (u16*)(ws);                    //  8 MiB: x bf16 [4096][1024]
  u16* Wcat = (u16*)(ws + (8  << 20));       //  6 MiB: [Wq;Wk;Wv] bf16 [3072][1024]
  u16* Wob  = (u16*)(ws + (14 << 20));       //  2 MiB: Wo bf16 [1024][1024]
  u16* QKV  = (u16*)(ws + (16 << 20));       // 24 MiB: [4096][3072]
  u16* Oatt = (u16*)(ws + (40 << 20));       //  8 MiB: [4096][1024]

  cvt_all<<<8192, 256, 0, stream>>>(x, Wq, Wk, Wv, Wo, xb, Wcat, Wob);
  gemm128<1><<<768, 256, 0, stream>>>(xb, Wcat, QKV, 3072, 1024, 24);
  attn_swa<<<dim3(32, 32), 256, 0, stream>>>(QKV, Oatt);
  gemm128<0><<<256, 256, 0, stream>>>(Oatt, Wob, d_out, 1024, 1024, 8);
}

// Round 8
// 94.510 us; speedup vs baseline: 1.3673x; 1.0239x over previous
//
#include <hip/hip_runtime.h>
#include <cstdint>

typedef uint16_t u16;
typedef __attribute__((ext_vector_type(8))) short short8;
typedef __attribute__((ext_vector_type(4))) float f32x4;

__device__ __forceinline__ u16 f2bf(float f) {
  uint32_t u = __float_as_uint(f);
  u += 0x7fff + ((u >> 16) & 1);   // RNE
  return (u16)(u >> 16);
}
// pack 2 floats -> 2 bf16 (round-half-up): a in low half, b in high half
__device__ __forceinline__ uint32_t pk2bf(float a, float b) {
  uint32_t ua = __float_as_uint(a) + 0x8000u;
  uint32_t ub = __float_as_uint(b) + 0x8000u;
  return (ua >> 16) | (ub & 0xFFFF0000u);
}

#define GLL16(gp, lp) __builtin_amdgcn_global_load_lds( \
    (__attribute__((address_space(1))) void*)(gp), \
    (__attribute__((address_space(3))) void*)(lp), 16, 0, 0)

#define SBAR()       __builtin_amdgcn_s_barrier()
#define WAIT_LGKM0() asm volatile("s_waitcnt lgkmcnt(0)" ::: "memory")
#define WAIT_VM(N)   asm volatile("s_waitcnt vmcnt(" #N ")" ::: "memory")
#define MEMBAR()     asm volatile("" ::: "memory")

// ---------------- fused f32 -> bf16 convert; Wq is pre-scaled by d^-0.5 * log2(e) ----------------
__global__ void cvt_all(const float* __restrict__ x,  const float* __restrict__ wq,
                        const float* __restrict__ wk, const float* __restrict__ wv,
                        const float* __restrict__ wo,
                        u16* __restrict__ xb, u16* __restrict__ wcat, u16* __restrict__ wob) {
  int i = blockIdx.x * 256 + threadIdx.x;
  const float4* src; ushort4* dst; int off; float sc = 1.0f;
  if (i < 1048576)      { src = (const float4*)x;  dst = (ushort4*)xb;              off = i; }
  else if (i < 1310720) { src = (const float4*)wq; dst = (ushort4*)wcat;            off = i - 1048576;
                          sc = 0.18033688011112042f; }   // 0.125 * log2(e), folded into Q
  else if (i < 1572864) { src = (const float4*)wk; dst = (ushort4*)wcat + 262144;   off = i - 1310720; }
  else if (i < 1835008) { src = (const float4*)wv; dst = (ushort4*)wcat + 524288;   off = i - 1572864; }
  else                  { src = (const float4*)wo; dst = (ushort4*)wob;             off = i - 1835008; }
  float4 v = src[off];
  ushort4 o;
  o.x = f2bf(v.x * sc); o.y = f2bf(v.y * sc); o.z = f2bf(v.z * sc); o.w = f2bf(v.w * sc);
  dst[off] = o;
}

// ---------------- 128x128 counted-vmcnt GEMM: C[m][n] = sum_k A[m][k]*B[n][k] ----------------
template<int OUT_BF16>
__global__ __launch_bounds__(256, 2) void gemm128(const u16* __restrict__ A,
                                                  const u16* __restrict__ B,
                                                  void* __restrict__ Cout,
                                                  int N, int K, int ntN) {
  __shared__ u16 sm[2][2][128 * 64];   // [dbuf][A,B][row][k] 64 KiB
  const int tid  = threadIdx.x;
  const int lane = tid & 63, w = tid >> 6;
  const int wr = w >> 1, wc = w & 1;
  const int g = lane >> 4, lr = lane & 15;

  const int cpx = gridDim.x >> 3;
  const int id  = blockIdx.x;
  const int sw  = (id & 7) * cpx + (id >> 3);
  const int row0 = (sw / ntN) * 128, col0 = (sw % ntN) * 128;
  const int T = K >> 6;

  f32x4 acc[4][4];
  #pragma unroll
  for (int i = 0; i < 4; ++i)
    #pragma unroll
    for (int j = 0; j < 4; ++j) acc[i][j] = (f32x4){0.f, 0.f, 0.f, 0.f};

  auto STAGE = [&](int kt, int bufi) {
    #pragma unroll
    for (int ab = 0; ab < 2; ++ab) {
      const u16* __restrict__ src = ab ? B : A;
      const int rb = ab ? col0 : row0;
      #pragma unroll
      for (int j = 0; j < 4; ++j) {
        int r  = j * 32 + w * 8 + (lane >> 3);
        int sb = ((lane & 7) << 4) ^ ((r & 7) << 4);
        const u16* gp = src + (size_t)(rb + r) * K + kt * 64 + (sb >> 1);
        GLL16(gp, &sm[bufi][ab][(size_t)(j * 32 + w * 8) * 64]);
      }
    }
  };

  STAGE(0, 0); STAGE(1, 1);
  WAIT_VM(8); SBAR(); MEMBAR();

  for (int t = 0; t < T; ++t) {
    const int cur = t & 1;
    short8 a[4][2], b[4][2];
    #pragma unroll
    for (int mm = 0; mm < 4; ++mm)
      #pragma unroll
      for (int kh = 0; kh < 2; ++kh) {
        int row = wr * 64 + mm * 16 + lr;
        int col = (kh * 64 + g * 16) ^ ((row & 7) << 4);
        a[mm][kh] = *(const short8*)((const char*)&sm[cur][0][0] + row * 128 + col);
      }
    #pragma unroll
    for (int nn = 0; nn < 4; ++nn)
      #pragma unroll
      for (int kh = 0; kh < 2; ++kh) {
        int row = wc * 64 + nn * 16 + lr;
        int col = (kh * 64 + g * 16) ^ ((row & 7) << 4);
        b[nn][kh] = *(const short8*)((const char*)&sm[cur][1][0] + row * 128 + col);
      }
    WAIT_LGKM0(); MEMBAR(); SBAR(); MEMBAR();

    if (t + 2 < T) STAGE(t + 2, cur);

    __builtin_amdgcn_s_setprio(1);
    #pragma unroll
    for (int kh = 0; kh < 2; ++kh)
      #pragma unroll
      for (int mm = 0; mm < 4; ++mm)
        #pragma unroll
        for (int nn = 0; nn < 4; ++nn)
          acc[mm][nn] = __builtin_amdgcn_mfma_f32_16x16x32_bf16(
              a[mm][kh], b[nn][kh], acc[mm][nn], 0, 0, 0);
    __builtin_amdgcn_s_setprio(0);

    if (t + 1 < T) {
      if (t + 2 < T) { WAIT_VM(8); } else { WAIT_VM(0); }
      SBAR(); MEMBAR();
    }
  }

  #pragma unroll
  for (int i = 0; i < 4; ++i)
    #pragma unroll
    for (int j = 0; j < 4; ++j)
      #pragma unroll
      for (int ri = 0; ri < 4; ++ri) {
        int rr = row0 + wr * 64 + i * 16 + g * 4 + ri;
        int cc = col0 + wc * 64 + j * 16 + lr;
        if (OUT_BF16) ((u16*)Cout)[(size_t)rr * N + cc] = f2bf(acc[i][j][ri]);
        else          ((float*)Cout)[(size_t)rr * N + cc] = acc[i][j][ri];
      }
}

// ---------------- Flash sliding-window attention (v4) ----------------
// v3 + scale folded into Wq (no per-score mul), clean-tile fast path (no mask ops on
// interior tiles; single unsigned-cmp mask on boundary tiles), round-half-up pair pack.
__global__ __launch_bounds__(256) void attn_swa(const u16* __restrict__ QKV, u16* __restrict__ O) {
  const int S = 2048;
  const int qb = blockIdx.x * 64;
  const int b = blockIdx.y >> 4, h = blockIdx.y & 15;
  const int tid = threadIdx.x;
  const int lane = tid & 63, w = tid >> 6;
  const int g = lane >> 4, lr = lane & 15;

  __shared__ u16 Klds[2][64 * 64];   // [64 keys][64 d], rows 128B, byte ^= (row&7)<<4
  __shared__ u16 Vt[64][72];         // V^T [d][key], pitch 144B (single buffer)
  __shared__ u16 Plds[4][16][72];    // per-wave P^T [q][key 0..63], pitch 144B

  const u16* Qb = QKV + (size_t)b * S * 3072 + h * 64;
  const u16* Kb = QKV + (size_t)b * S * 3072 + 1024 + h * 64;
  const u16* Vb = QKV + (size_t)b * S * 3072 + 2048 + h * 64;

  const int qw = qb + w * 16;
  short8 qf0 = *(const short8*)(Qb + (size_t)(qw + lr) * 3072 + g * 8);
  short8 qf1 = *(const short8*)(Qb + (size_t)(qw + lr) * 3072 + 32 + g * 8);

  float ls = 0.f;
  f32x4 accO[4];
  #pragma unroll
  for (int i = 0; i < 4; ++i) accO[i] = (f32x4){0.f, 0.f, 0.f, 0.f};

  int ks = qb - 511; if (ks < 0) ks = 0; ks &= ~63;
  const int ke = qb + 63;
  const int nt = ((ke - ks) >> 6) + 1;

  short8 vreg0, vreg1;

  auto STAGE_K = [&](int kb, int buf) {
    #pragma unroll
    for (int c = 0; c < 2; ++c) {
      int r  = c * 32 + w * 8 + (lane >> 3);
      int sb = ((lane & 7) << 4) ^ ((r & 7) << 4);
      const u16* gp = Kb + (size_t)(kb + r) * 3072 + (sb >> 1);
      u16* lp = Klds[buf] + c * 2048 + w * 512;
      GLL16(gp, lp);
    }
  };
  auto LOAD_V = [&](int kb) {
    vreg0 = *(const short8*)(Vb + (size_t)(kb + lane) * 3072 + w * 8);
    vreg1 = *(const short8*)(Vb + (size_t)(kb + lane) * 3072 + w * 8 + 32);
  };
  auto WRITE_V = [&]() {
    #pragma unroll
    for (int j = 0; j < 8; ++j) Vt[w * 8 + j][lane]      = (u16)vreg0[j];
    #pragma unroll
    for (int j = 0; j < 8; ++j) Vt[w * 8 + 32 + j][lane] = (u16)vreg1[j];
  };

  STAGE_K(ks, 0);
  LOAD_V(ks);
  __syncthreads();
  WRITE_V();
  __syncthreads();

  int cur = 0, kb = ks;
  for (int t = 0; t < nt; ++t, kb += 64) {
    const int nxt = cur ^ 1;
    const bool more = (t + 1 < nt);
    if (more) { STAGE_K(kb + 64, nxt); LOAD_V(kb + 64); }

    // ---- QK^T (swapped): D[key][query]; scores already scaled by d^-0.5*log2e via Wq ----
    float p[4][4];   // [st][ri] = score/P for key kb+st*16+g*4+ri, query qw+lr
    #pragma unroll
    for (int st = 0; st < 4; ++st) {
      f32x4 c4 = (f32x4){0.f, 0.f, 0.f, 0.f};
      int r = st * 16 + lr;
      int swz = (r & 7) << 4;
      const char* krow = (const char*)(Klds[cur]) + r * 128;
      short8 kf0 = *(const short8*)(krow + ((g * 16) ^ swz));
      short8 kf1 = *(const short8*)(krow + ((64 + g * 16) ^ swz));
      __builtin_amdgcn_s_setprio(1);
      c4 = __builtin_amdgcn_mfma_f32_16x16x32_bf16(kf0, qf0, c4, 0, 0, 0);
      c4 = __builtin_amdgcn_mfma_f32_16x16x32_bf16(kf1, qf1, c4, 0, 0, 0);
      __builtin_amdgcn_s_setprio(0);
      #pragma unroll
      for (int ri = 0; ri < 4; ++ri) p[st][ri] = c4[ri];
    }

    // ---- exp2; mask only on boundary tiles (wave-uniform branch, no barriers inside) ----
    const bool clean = (kb + 63 <= qw) && (qw + 15 - kb < 512);
    if (clean) {
      #pragma unroll
      for (int st = 0; st < 4; ++st)
        #pragma unroll
        for (int ri = 0; ri < 4; ++ri)
          p[st][ri] = __builtin_amdgcn_exp2f(p[st][ri]);
    } else {
      const int base = qw + lr - kb;   // qi - kb
      #pragma unroll
      for (int st = 0; st < 4; ++st)
        #pragma unroll
        for (int ri = 0; ri < 4; ++ri) {
          float e = __builtin_amdgcn_exp2f(p[st][ri]);
          // valid iff 0 <= qi-ki < 512, one unsigned compare
          p[st][ri] = ((uint32_t)(base - (st * 16 + g * 4 + ri)) < 512u) ? e : 0.f;
        }
    }

    // ---- lane-local row sum + cross-group reduce ----
    {
      float s = 0.f;
      #pragma unroll
      for (int st = 0; st < 4; ++st)
        #pragma unroll
        for (int ri = 0; ri < 4; ++ri) s += p[st][ri];
      s += __shfl_xor(s, 16);
      s += __shfl_xor(s, 32);
      ls += s;
    }

    // ---- P^T -> LDS: 4x b64, conflict-free ----
    #pragma unroll
    for (int st = 0; st < 4; ++st) {
      uint2 u2;
      u2.x = pk2bf(p[st][0], p[st][1]);
      u2.y = pk2bf(p[st][2], p[st][3]);
      *(uint2*)(&Plds[w][lr][st * 16 + g * 4]) = u2;
    }

    // ---- PV ----
    short8 pf0 = *(const short8*)(&Plds[w][lr][g * 8]);
    short8 pf1 = *(const short8*)(&Plds[w][lr][32 + g * 8]);
    __builtin_amdgcn_s_setprio(1);
    #pragma unroll
    for (int dt = 0; dt < 4; ++dt) {
      short8 vf0 = *(const short8*)(&Vt[dt * 16 + lr][g * 8]);
      short8 vf1 = *(const short8*)(&Vt[dt * 16 + lr][32 + g * 8]);
      accO[dt] = __builtin_amdgcn_mfma_f32_16x16x32_bf16(pf0, vf0, accO[dt], 0, 0, 0);
      accO[dt] = __builtin_amdgcn_mfma_f32_16x16x32_bf16(pf1, vf1, accO[dt], 0, 0, 0);
    }
    __builtin_amdgcn_s_setprio(0);

    __syncthreads();
    if (more) WRITE_V();
    __syncthreads();
    cur = nxt;
  }

  float lsq[4];
  #pragma unroll
  for (int ri = 0; ri < 4; ++ri) lsq[ri] = __shfl(ls, g * 4 + ri);
  #pragma unroll
  for (int dt = 0; dt < 4; ++dt)
    #pragma unroll
    for (int ri = 0; ri < 4; ++ri) {
      int qi = qw + g * 4 + ri;
      O[(size_t)(b * S + qi) * 1024 + h * 64 + dt * 16 + lr] = f2bf(accO[dt][ri] / lsq[ri]);
    }
}

// ---------------- launch ----------------
extern "C" void kernel_launch(void* const* d_in, const int* in_sizes, int n_in,
                              void* d_out, int out_size, void* d_ws, size_t ws_size,
                              hipStream_t stream) {
  const float* x  = (const float*)d_in[0];
  const float* Wq = (const float*)d_in[1];
  const float* Wk = (const float*)d_in[2];
  const float* Wv = (const float*)d_in[3];
  const float* Wo = (const float*)d_in[4];

  char* ws = (char*)d_ws;
  u16* xb   = (u16*)(ws);                    //  8 MiB: x bf16 [4096][1024]
  u16* Wcat = (u16*)(ws + (8  << 20));       //  6 MiB: [Wq;Wk;Wv] bf16 [3072][1024]
  u16* Wob  = (u16*)(ws + (14 << 20));       //  2 MiB: Wo bf16 [1024][1024]
  u16* QKV  = (u16*)(ws + (16 << 20));       // 24 MiB: [4096][3072]
  u16* Oatt = (u16*)(ws + (40 << 20));       //  8 MiB: [4096][1024]

  cvt_all<<<8192, 256, 0, stream>>>(x, Wq, Wk, Wv, Wo, xb, Wcat, Wob);
  gemm128<1><<<768, 256, 0, stream>>>(xb, Wcat, QKV, 3072, 1024, 24);
  attn_swa<<<dim3(32, 32), 256, 0, stream>>>(QKV, Oatt);
  gemm128<0><<<256, 256, 0, stream>>>(Oatt, Wob, d_out, 1024, 1024, 8);
}

// Round 9
// 91.010 us; speedup vs baseline: 1.4199x; 1.0385x over previous
//
#include <hip/hip_runtime.h>
#include <cstdint>

typedef uint16_t u16;
typedef __attribute__((ext_vector_type(8))) short short8;
typedef __attribute__((ext_vector_type(4))) float f32x4;

__device__ __forceinline__ u16 f2bf(float f) {
  uint32_t u = __float_as_uint(f);
  u += 0x7fff + ((u >> 16) & 1);   // RNE
  return (u16)(u >> 16);
}
// pack 2 floats -> 2 bf16 (round-half-up): a low, b high
__device__ __forceinline__ uint32_t pk2bf(float a, float b) {
  uint32_t ua = __float_as_uint(a) + 0x8000u;
  uint32_t ub = __float_as_uint(b) + 0x8000u;
  return (ua >> 16) | (ub & 0xFFFF0000u);
}

#define GLL16(gp, lp) __builtin_amdgcn_global_load_lds( \
    (__attribute__((address_space(1))) void*)(gp), \
    (__attribute__((address_space(3))) void*)(lp), 16, 0, 0)

#define SBAR()       __builtin_amdgcn_s_barrier()
#define WAIT_LGKM0() asm volatile("s_waitcnt lgkmcnt(0)" ::: "memory")
#define WAIT_VM(N)   asm volatile("s_waitcnt vmcnt(" #N ")" ::: "memory")
#define MEMBAR()     asm volatile("" ::: "memory")

// ---------------- fused f32 -> bf16 convert; Wq pre-scaled by d^-0.5 * log2(e) ----------------
__global__ void cvt_all(const float* __restrict__ x,  const float* __restrict__ wq,
                        const float* __restrict__ wk, const float* __restrict__ wv,
                        const float* __restrict__ wo,
                        u16* __restrict__ xb, u16* __restrict__ wcat, u16* __restrict__ wob) {
  int i = blockIdx.x * 256 + threadIdx.x;
  const float4* src; ushort4* dst; int off; float sc = 1.0f;
  if (i < 1048576)      { src = (const float4*)x;  dst = (ushort4*)xb;              off = i; }
  else if (i < 1310720) { src = (const float4*)wq; dst = (ushort4*)wcat;            off = i - 1048576;
                          sc = 0.18033688011112042f; }   // 0.125 * log2(e)
  else if (i < 1572864) { src = (const float4*)wk; dst = (ushort4*)wcat + 262144;   off = i - 1310720; }
  else if (i < 1835008) { src = (const float4*)wv; dst = (ushort4*)wcat + 524288;   off = i - 1572864; }
  else                  { src = (const float4*)wo; dst = (ushort4*)wob;             off = i - 1835008; }
  float4 v = src[off];
  ushort4 o;
  o.x = f2bf(v.x * sc); o.y = f2bf(v.y * sc); o.z = f2bf(v.z * sc); o.w = f2bf(v.w * sc);
  dst[off] = o;
}

// ---------------- 128x128 counted-vmcnt GEMM (unchanged) ----------------
template<int OUT_BF16>
__global__ __launch_bounds__(256, 2) void gemm128(const u16* __restrict__ A,
                                                  const u16* __restrict__ B,
                                                  void* __restrict__ Cout,
                                                  int N, int K, int ntN) {
  __shared__ u16 sm[2][2][128 * 64];
  const int tid  = threadIdx.x;
  const int lane = tid & 63, w = tid >> 6;
  const int wr = w >> 1, wc = w & 1;
  const int g = lane >> 4, lr = lane & 15;

  const int cpx = gridDim.x >> 3;
  const int id  = blockIdx.x;
  const int sw  = (id & 7) * cpx + (id >> 3);
  const int row0 = (sw / ntN) * 128, col0 = (sw % ntN) * 128;
  const int T = K >> 6;

  f32x4 acc[4][4];
  #pragma unroll
  for (int i = 0; i < 4; ++i)
    #pragma unroll
    for (int j = 0; j < 4; ++j) acc[i][j] = (f32x4){0.f, 0.f, 0.f, 0.f};

  auto STAGE = [&](int kt, int bufi) {
    #pragma unroll
    for (int ab = 0; ab < 2; ++ab) {
      const u16* __restrict__ src = ab ? B : A;
      const int rb = ab ? col0 : row0;
      #pragma unroll
      for (int j = 0; j < 4; ++j) {
        int r  = j * 32 + w * 8 + (lane >> 3);
        int sb = ((lane & 7) << 4) ^ ((r & 7) << 4);
        const u16* gp = src + (size_t)(rb + r) * K + kt * 64 + (sb >> 1);
        GLL16(gp, &sm[bufi][ab][(size_t)(j * 32 + w * 8) * 64]);
      }
    }
  };

  STAGE(0, 0); STAGE(1, 1);
  WAIT_VM(8); SBAR(); MEMBAR();

  for (int t = 0; t < T; ++t) {
    const int cur = t & 1;
    short8 a[4][2], b[4][2];
    #pragma unroll
    for (int mm = 0; mm < 4; ++mm)
      #pragma unroll
      for (int kh = 0; kh < 2; ++kh) {
        int row = wr * 64 + mm * 16 + lr;
        int col = (kh * 64 + g * 16) ^ ((row & 7) << 4);
        a[mm][kh] = *(const short8*)((const char*)&sm[cur][0][0] + row * 128 + col);
      }
    #pragma unroll
    for (int nn = 0; nn < 4; ++nn)
      #pragma unroll
      for (int kh = 0; kh < 2; ++kh) {
        int row = wc * 64 + nn * 16 + lr;
        int col = (kh * 64 + g * 16) ^ ((row & 7) << 4);
        b[nn][kh] = *(const short8*)((const char*)&sm[cur][1][0] + row * 128 + col);
      }
    WAIT_LGKM0(); MEMBAR(); SBAR(); MEMBAR();

    if (t + 2 < T) STAGE(t + 2, cur);

    __builtin_amdgcn_s_setprio(1);
    #pragma unroll
    for (int kh = 0; kh < 2; ++kh)
      #pragma unroll
      for (int mm = 0; mm < 4; ++mm)
        #pragma unroll
        for (int nn = 0; nn < 4; ++nn)
          acc[mm][nn] = __builtin_amdgcn_mfma_f32_16x16x32_bf16(
              a[mm][kh], b[nn][kh], acc[mm][nn], 0, 0, 0);
    __builtin_amdgcn_s_setprio(0);

    if (t + 1 < T) {
      if (t + 2 < T) { WAIT_VM(8); } else { WAIT_VM(0); }
      SBAR(); MEMBAR();
    }
  }

  #pragma unroll
  for (int i = 0; i < 4; ++i)
    #pragma unroll
    for (int j = 0; j < 4; ++j)
      #pragma unroll
      for (int ri = 0; ri < 4; ++ri) {
        int rr = row0 + wr * 64 + i * 16 + g * 4 + ri;
        int cc = col0 + wc * 64 + j * 16 + lr;
        if (OUT_BF16) ((u16*)Cout)[(size_t)rr * N + cc] = f2bf(acc[i][j][ri]);
        else          ((float*)Cout)[(size_t)rr * N + cc] = acc[i][j][ri];
      }
}

// ---------------- Flash sliding-window attention (v5: QBLK=128, 32 q/wave) ----------------
// Block = 256 thr = 4 waves; block owns (b, h, 128 queries); wave owns 32 queries as two
// 16-query MFMA column groups (qg). Per 64-key tile: K-frag LDS reads shared across qg ->
// 32 MFMAs per wave per tile at the same staging/barrier cost as v4's 16.
__global__ __launch_bounds__(256) void attn_swa(const u16* __restrict__ QKV, u16* __restrict__ O) {
  const int S = 2048;
  const int qb = blockIdx.x * 128;
  const int b = blockIdx.y >> 4, h = blockIdx.y & 15;
  const int tid = threadIdx.x;
  const int lane = tid & 63, w = tid >> 6;
  const int g = lane >> 4, lr = lane & 15;

  __shared__ u16 Klds[2][64 * 64];   // [64 keys][64 d], rows 128B, byte ^= (row&7)<<4
  __shared__ u16 Vt[64][72];         // V^T [d][key], pitch 144B (single buffer)
  __shared__ u16 Plds[4][32][72];    // per-wave P^T [q 0..31][key 0..63], pitch 144B

  const u16* Qb = QKV + (size_t)b * S * 3072 + h * 64;
  const u16* Kb = QKV + (size_t)b * S * 3072 + 1024 + h * 64;
  const u16* Vb = QKV + (size_t)b * S * 3072 + 2048 + h * 64;

  const int qw = qb + w * 32;
  // Q A-frags: [qg][kh], query row = qw + qg*16 + lr, d = kh*32 + g*8 ..
  short8 qf[2][2];
  #pragma unroll
  for (int qg = 0; qg < 2; ++qg)
    #pragma unroll
    for (int kh = 0; kh < 2; ++kh)
      qf[qg][kh] = *(const short8*)(Qb + (size_t)(qw + qg * 16 + lr) * 3072 + kh * 32 + g * 8);

  float ls[2] = {0.f, 0.f};
  f32x4 accO[2][4];
  #pragma unroll
  for (int qg = 0; qg < 2; ++qg)
    #pragma unroll
    for (int i = 0; i < 4; ++i) accO[qg][i] = (f32x4){0.f, 0.f, 0.f, 0.f};

  int ks = qb - 511; if (ks < 0) ks = 0; ks &= ~63;
  const int ke = qb + 127;
  const int nt = ((ke - ks) >> 6) + 1;

  short8 vreg0, vreg1;

  auto STAGE_K = [&](int kb, int buf) {
    #pragma unroll
    for (int c = 0; c < 2; ++c) {
      int r  = c * 32 + w * 8 + (lane >> 3);
      int sb = ((lane & 7) << 4) ^ ((r & 7) << 4);
      const u16* gp = Kb + (size_t)(kb + r) * 3072 + (sb >> 1);
      u16* lp = Klds[buf] + c * 2048 + w * 512;
      GLL16(gp, lp);
    }
  };
  auto LOAD_V = [&](int kb) {
    vreg0 = *(const short8*)(Vb + (size_t)(kb + lane) * 3072 + w * 8);
    vreg1 = *(const short8*)(Vb + (size_t)(kb + lane) * 3072 + w * 8 + 32);
  };
  auto WRITE_V = [&]() {
    #pragma unroll
    for (int j = 0; j < 8; ++j) Vt[w * 8 + j][lane]      = (u16)vreg0[j];
    #pragma unroll
    for (int j = 0; j < 8; ++j) Vt[w * 8 + 32 + j][lane] = (u16)vreg1[j];
  };

  STAGE_K(ks, 0);
  LOAD_V(ks);
  __syncthreads();
  WRITE_V();
  __syncthreads();

  int cur = 0, kb = ks;
  for (int t = 0; t < nt; ++t, kb += 64) {
    const int nxt = cur ^ 1;
    const bool more = (t + 1 < nt);
    if (more) { STAGE_K(kb + 64, nxt); LOAD_V(kb + 64); }

    // ---- QK^T (swapped): per key-subtile read K-frags once, 4 MFMAs (2 kh x 2 qg) ----
    float p[2][4][4];   // [qg][st][ri]
    #pragma unroll
    for (int st = 0; st < 4; ++st) {
      f32x4 c4[2];
      c4[0] = (f32x4){0.f, 0.f, 0.f, 0.f};
      c4[1] = (f32x4){0.f, 0.f, 0.f, 0.f};
      int r = st * 16 + lr;
      int swz = (r & 7) << 4;
      const char* krow = (const char*)(Klds[cur]) + r * 128;
      short8 kf0 = *(const short8*)(krow + ((g * 16) ^ swz));
      short8 kf1 = *(const short8*)(krow + ((64 + g * 16) ^ swz));
      __builtin_amdgcn_s_setprio(1);
      c4[0] = __builtin_amdgcn_mfma_f32_16x16x32_bf16(kf0, qf[0][0], c4[0], 0, 0, 0);
      c4[1] = __builtin_amdgcn_mfma_f32_16x16x32_bf16(kf0, qf[1][0], c4[1], 0, 0, 0);
      c4[0] = __builtin_amdgcn_mfma_f32_16x16x32_bf16(kf1, qf[0][1], c4[0], 0, 0, 0);
      c4[1] = __builtin_amdgcn_mfma_f32_16x16x32_bf16(kf1, qf[1][1], c4[1], 0, 0, 0);
      __builtin_amdgcn_s_setprio(0);
      #pragma unroll
      for (int ri = 0; ri < 4; ++ri) { p[0][st][ri] = c4[0][ri]; p[1][st][ri] = c4[1][ri]; }
    }

    // ---- exp2 + mask (clean fast path per query group; wave-uniform branches) ----
    #pragma unroll
    for (int qg = 0; qg < 2; ++qg) {
      const int q0 = qw + qg * 16;
      const bool clean = (kb + 63 <= q0) && (q0 + 15 - kb < 512);
      if (clean) {
        #pragma unroll
        for (int st = 0; st < 4; ++st)
          #pragma unroll
          for (int ri = 0; ri < 4; ++ri)
            p[qg][st][ri] = __builtin_amdgcn_exp2f(p[qg][st][ri]);
      } else {
        const int base = q0 + lr - kb;
        #pragma unroll
        for (int st = 0; st < 4; ++st)
          #pragma unroll
          for (int ri = 0; ri < 4; ++ri) {
            float e = __builtin_amdgcn_exp2f(p[qg][st][ri]);
            p[qg][st][ri] = ((uint32_t)(base - (st * 16 + g * 4 + ri)) < 512u) ? e : 0.f;
          }
      }
      float s = 0.f;
      #pragma unroll
      for (int st = 0; st < 4; ++st)
        #pragma unroll
        for (int ri = 0; ri < 4; ++ri) s += p[qg][st][ri];
      s += __shfl_xor(s, 16);
      s += __shfl_xor(s, 32);
      ls[qg] += s;

      #pragma unroll
      for (int st = 0; st < 4; ++st) {
        uint2 u2;
        u2.x = pk2bf(p[qg][st][0], p[qg][st][1]);
        u2.y = pk2bf(p[qg][st][2], p[qg][st][3]);
        *(uint2*)(&Plds[w][qg * 16 + lr][st * 16 + g * 4]) = u2;
      }
    }

    // ---- PV: V-frags shared across qg ----
    short8 pf[2][2];
    #pragma unroll
    for (int qg = 0; qg < 2; ++qg) {
      pf[qg][0] = *(const short8*)(&Plds[w][qg * 16 + lr][g * 8]);
      pf[qg][1] = *(const short8*)(&Plds[w][qg * 16 + lr][32 + g * 8]);
    }
    __builtin_amdgcn_s_setprio(1);
    #pragma unroll
    for (int dt = 0; dt < 4; ++dt) {
      short8 vf0 = *(const short8*)(&Vt[dt * 16 + lr][g * 8]);
      short8 vf1 = *(const short8*)(&Vt[dt * 16 + lr][32 + g * 8]);
      accO[0][dt] = __builtin_amdgcn_mfma_f32_16x16x32_bf16(pf[0][0], vf0, accO[0][dt], 0, 0, 0);
      accO[1][dt] = __builtin_amdgcn_mfma_f32_16x16x32_bf16(pf[1][0], vf0, accO[1][dt], 0, 0, 0);
      accO[0][dt] = __builtin_amdgcn_mfma_f32_16x16x32_bf16(pf[0][1], vf1, accO[0][dt], 0, 0, 0);
      accO[1][dt] = __builtin_amdgcn_mfma_f32_16x16x32_bf16(pf[1][1], vf1, accO[1][dt], 0, 0, 0);
    }
    __builtin_amdgcn_s_setprio(0);

    __syncthreads();
    if (more) WRITE_V();
    __syncthreads();
    cur = nxt;
  }

  #pragma unroll
  for (int qg = 0; qg < 2; ++qg) {
    float lsq[4];
    #pragma unroll
    for (int ri = 0; ri < 4; ++ri) lsq[ri] = __shfl(ls[qg], g * 4 + ri);
    #pragma unroll
    for (int dt = 0; dt < 4; ++dt)
      #pragma unroll
      for (int ri = 0; ri < 4; ++ri) {
        int qi = qw + qg * 16 + g * 4 + ri;
        O[(size_t)(b * S + qi) * 1024 + h * 64 + dt * 16 + lr] = f2bf(accO[qg][dt][ri] / lsq[ri]);
      }
  }
}

// ---------------- launch ----------------
extern "C" void kernel_launch(void* const* d_in, const int* in_sizes, int n_in,
                              void* d_out, int out_size, void* d_ws, size_t ws_size,
                              hipStream_t stream) {
  const float* x  = (const float*)d_in[0];
  const float* Wq = (const float*)d_in[1];
  const float* Wk = (const float*)d_in[2];
  const float* Wv = (const float*)d_in[3];
  const float* Wo = (const float*)d_in[4];

  char* ws = (char*)d_ws;
  u16* xb   = (u16*)(ws);                    //  8 MiB: x bf16 [4096][1024]
  u16* Wcat = (u16*)(ws + (8  << 20));       //  6 MiB: [Wq;Wk;Wv] bf16 [3072][1024]
  u16* Wob  = (u16*)(ws + (14 << 20));       //  2 MiB: Wo bf16 [1024][1024]
  u16* QKV  = (u16*)(ws + (16 << 20));       // 24 MiB: [4096][3072]
  u16* Oatt = (u16*)(ws + (40 << 20));       //  8 MiB: [4096][1024]

  cvt_all<<<8192, 256, 0, stream>>>(x, Wq, Wk, Wv, Wo, xb, Wcat, Wob);
  gemm128<1><<<768, 256, 0, stream>>>(xb, Wcat, QKV, 3072, 1024, 24);
  attn_swa<<<dim3(16, 32), 256, 0, stream>>>(QKV, Oatt);
  gemm128<0><<<256, 256, 0, stream>>>(Oatt, Wob, d_out, 1024, 1024, 8);
}